// Round 7
// baseline (215.714 us; speedup 1.0000x reference)
//
#include <hip/hip_runtime.h>
#include <hip/hip_bf16.h>

// Problem constants (fixed by the reference)
#define NN 8192   // nodes per side
#define ED 128    // embedding dim E
#define DD 64     // attention dim D
#define KK 32     // neighbors per node
#define MM 4      // metapaths

typedef __attribute__((ext_vector_type(8))) short short8;   // 8 bf16 (4 VGPRs)
typedef __attribute__((ext_vector_type(4))) float f32x4;    // MFMA acc
typedef __attribute__((ext_vector_type(2))) float f32x2;    // packed f32 pair

// raw v_exp_f32 (2^x); fallback multiplies back to e-base expf
#if __has_builtin(__builtin_amdgcn_exp2f)
#define EXP2R(x) __builtin_amdgcn_exp2f(x)
#else
#define EXP2R(x) __expf((x) * 0.6931471805599453f)
#endif
#define C2LOG2E 2.8853900817779268f   // 2*log2(e)

#if __has_builtin(__builtin_elementwise_fma)
#define FMA2(a, b, c) __builtin_elementwise_fma((a), (b), (c))
#else
__device__ __forceinline__ f32x2 FMA2(f32x2 a, f32x2 b, f32x2 c)
{
    f32x2 r;
    r.x = fmaf(a.x, b.x, c.x);
    r.y = fmaf(a.y, b.y, c.y);
    return r;
}
#endif

// tanh from pre-scaled arg v = x*2*log2(e): 1 - 2*rcp(2^v + 1)
__device__ __forceinline__ float ftanh_pre(float v)
{
    return fmaf(-2.0f, __builtin_amdgcn_rcpf(EXP2R(v) + 1.0f), 1.0f);
}
// plain fast tanh (sem epilogue)
__device__ __forceinline__ float ftanh(float x)
{
    return ftanh_pre(x * C2LOG2E);
}

__device__ __forceinline__ unsigned short f2bf(float x)
{
    __hip_bfloat16 b = __float2bfloat16(x);
    return *reinterpret_cast<unsigned short*>(&b);
}
__device__ __forceinline__ float bflo(unsigned int u) { return __uint_as_float(u << 16); }
__device__ __forceinline__ float bfhi(unsigned int u) { return __uint_as_float(u & 0xFFFF0000u); }
__device__ __forceinline__ float readlane_f(float v, int lane)
{
    return __uint_as_float(__builtin_amdgcn_readlane(__float_as_uint(v), lane));
}

// DPP helpers. CTRL: 0xB1 = quad_perm xor1, 0x4E = quad_perm xor2,
// 0x141 = row_half_mirror (xor4-equivalent for 8-lane tree sums),
// 0x128 = row_ror:8 ((lane+8)%16 == lane^8 within a 16-lane row).
// VALU-only — replaces ds_bpermute shuffle hops.
template <int CTRL>
__device__ __forceinline__ float dpp_mov_f(float x)
{
    return __int_as_float(__builtin_amdgcn_update_dpp(
        0, __float_as_int(x), CTRL, 0xF, 0xF, true));
}
template <int CTRL>
__device__ __forceinline__ float dpp_add_f(float x)
{
    return x + dpp_mov_f<CTRL>(x);
}

// -------------------------------------------------------------------------
// prep_kernel: one launch for all input reformatting.
//  y=0: user f32->bf16   y=1: product f32->bf16   (x < 1024, 4 elems/thr)
//  y=2/3/4: V/W_p/W_q f32 [S,ED,DD] -> bf16 [S,DD,ED]  (x < 256)
// -------------------------------------------------------------------------
__global__ __launch_bounds__(256) void prep_kernel(
    const float* __restrict__ user, unsigned short* __restrict__ userB,
    const float* __restrict__ product, unsigned short* __restrict__ productB,
    const float* __restrict__ V, unsigned short* __restrict__ VT,
    const float* __restrict__ Wp, unsigned short* __restrict__ PT,
    const float* __restrict__ Wq, unsigned short* __restrict__ QT)
{
    const int y = blockIdx.y;
    if (y < 2) {
        const float* in = y ? product : user;
        unsigned short* out = y ? productB : userB;
        const int i = blockIdx.x * 256 + threadIdx.x;
        const float4 v = ((const float4*)in)[i];
        uint2 o;
        o.x = (unsigned int)f2bf(v.x) | ((unsigned int)f2bf(v.y) << 16);
        o.y = (unsigned int)f2bf(v.z) | ((unsigned int)f2bf(v.w) << 16);
        ((uint2*)out)[i] = o;
    } else {
        if (blockIdx.x >= 256) return;
        const float* in = (y == 2) ? V : (y == 3) ? Wp : Wq;
        unsigned short* out = (y == 2) ? VT : (y == 3) ? PT : QT;
        const int gid = blockIdx.x * 256 + threadIdx.x;
        const int s   = gid >> 13;          // ED*DD = 8192
        const int rem = gid & 8191;
        const int e   = rem >> 6;
        const int d   = rem & 63;
        out[((size_t)s * DD + d) * ED + e] = f2bf(in[gid]);
    }
}

// -------------------------------------------------------------------------
// proj3_mfma: three projection slices in ONE phase-0 launch (blockIdx.z):
//   z=0: ES0 = exp2((user  @ V0 + B0) * C) -> f32 outF0  (phase-0 attn)
//   z=1: EP0 = exp2((prod  @ Wp0)     * C) -> bf16 outB1 (phase-0 attn)
//   z=2: ES1 = exp2((prod  @ V1 + B1) * C) -> f32 outF2  (phase-1 attn;
//        independent of phase 0, so computed here off the critical path)
// grid: (NN/64, MM, 3).
// -------------------------------------------------------------------------
__global__ __launch_bounds__(256) void proj3_mfma(
    const unsigned short* __restrict__ emb0,  // userB [NN,ED]
    const unsigned short* __restrict__ Wt0,   // VT0 [MM,DD,ED]
    const float* __restrict__ Bias0,          // B_p0 [MM,DD]
    float* __restrict__ outF0,                // S  (ES0)
    const unsigned short* __restrict__ emb1,  // productB [NN,ED]
    const unsigned short* __restrict__ Wt1,   // PT0 [MM,DD,ED]
    unsigned short* __restrict__ outB1,       // PnB (EP0)
    const unsigned short* __restrict__ Wt2,   // VT1 [MM,DD,ED]
    const float* __restrict__ Bias2,          // B_p1 [MM,DD]
    float* __restrict__ outF2)                // S2 (ES1)
{
    const int z    = blockIdx.z;
    const int m    = blockIdx.y;
    const int tid  = threadIdx.x;
    const int wave = tid >> 6;
    const int lane = tid & 63;
    const int nrow = lane & 15;
    const int quad = lane >> 4;
    const int r0   = blockIdx.x * 64 + wave * 16;

    const unsigned short* embB = (z == 0) ? emb0 : emb1;
    const unsigned short* WtB  = (z == 0) ? Wt0 : (z == 1) ? Wt1 : Wt2;

    const short8* A8 = (const short8*)(embB + (size_t)(r0 + nrow) * ED);
    const short8* B8 = (const short8*)(WtB + (size_t)m * DD * ED);

    f32x4 acc0 = {0.f, 0.f, 0.f, 0.f};
    f32x4 acc1 = {0.f, 0.f, 0.f, 0.f};
    f32x4 acc2 = {0.f, 0.f, 0.f, 0.f};
    f32x4 acc3 = {0.f, 0.f, 0.f, 0.f};

    #pragma unroll
    for (int kq = 0; kq < 4; ++kq) {
        const short8 a = A8[kq * 4 + quad];
        const short8 b0 = B8[(0 * 16 + nrow) * 16 + kq * 4 + quad];
        const short8 b1 = B8[(1 * 16 + nrow) * 16 + kq * 4 + quad];
        const short8 b2 = B8[(2 * 16 + nrow) * 16 + kq * 4 + quad];
        const short8 b3 = B8[(3 * 16 + nrow) * 16 + kq * 4 + quad];
        acc0 = __builtin_amdgcn_mfma_f32_16x16x32_bf16(a, b0, acc0, 0, 0, 0);
        acc1 = __builtin_amdgcn_mfma_f32_16x16x32_bf16(a, b1, acc1, 0, 0, 0);
        acc2 = __builtin_amdgcn_mfma_f32_16x16x32_bf16(a, b2, acc2, 0, 0, 0);
        acc3 = __builtin_amdgcn_mfma_f32_16x16x32_bf16(a, b3, acc3, 0, 0, 0);
    }

    f32x4 accs[4] = {acc0, acc1, acc2, acc3};
    if (z == 1) {
        #pragma unroll
        for (int t = 0; t < 4; ++t) {
            const int d = t * 16 + nrow;
            #pragma unroll
            for (int reg = 0; reg < 4; ++reg) {
                const int r = r0 + quad * 4 + reg;
                outB1[((size_t)m * NN + r) * DD + d] =
                    f2bf(EXP2R(accs[t][reg] * C2LOG2E));
            }
        }
    } else {
        const float* Bi = (z == 0) ? Bias0 : Bias2;
        float* oF       = (z == 0) ? outF0 : outF2;
        #pragma unroll
        for (int t = 0; t < 4; ++t) {
            const int d = t * 16 + nrow;
            const float bv = Bi[m * DD + d];
            #pragma unroll
            for (int reg = 0; reg < 4; ++reg) {
                const int r = r0 + quad * 4 + reg;
                oF[((size_t)m * NN + r) * DD + d] =
                    EXP2R((accs[t][reg] + bv) * C2LOG2E);
            }
        }
    }
}

// -------------------------------------------------------------------------
// attn_sem_kernel v10: 16 nodes/block (8 waves), sem fused.
// T14 issue-early/use-late: ALL 64 H-agg row-gathers (2 nodes x 32 k) are
// issued at wave entry, right after the 8 Pn gathers — their ~300-cycle L2
// latency hides under the score loop + softmax (~2000 cyc VALU). H-agg is
// then pure readlane+pk_fma on resident registers (no load waits).
// Costs ~+64 VGPR held across softmax; occupancy cap (4 waves/SIMD at
// ~128 VGPR) stays above the measured 35%.
// grid: (NN/16, MM), block 512.
// -------------------------------------------------------------------------
__global__ __launch_bounds__(512) void attn_sem_kernel(
    const float* __restrict__ src,             // [NN,ED] f32
    const unsigned short* __restrict__ otherB, // [NN,ED] bf16
    const int*   __restrict__ nbrs,            // [MM,NN,KK]
    const float* __restrict__ S,               // [MM,NN,DD] f32 = ES
    const unsigned short* __restrict__ PnB,    // [MM,NN,DD] bf16 = EP
    const float* __restrict__ Xv,              // [MM,DD] f32
    unsigned short* __restrict__ HoutB,        // [MM,NN,ED] bf16
    const unsigned short* __restrict__ WqT,    // [MM,DD,ED] bf16
    const float* __restrict__ Bq,              // [MM,DD]
    const float* __restrict__ Qv,              // [MM,DD]
    float* __restrict__ bp)                    // [MM*512] beta partials
{
    // H staging: 16 rows x 64 packed-bf16 words, +4 words pad per row to
    // break the 256B-stride bank alignment for the ds_read_b128 fragments.
    __shared__ __align__(16) unsigned int lh[16][68];
    __shared__ float red_sh[4];

    const int m    = blockIdx.y;
    const int tid  = threadIdx.x;
    const int w    = tid >> 6;
    const int lane = tid & 63;
    const int g    = blockIdx.x * 8 + w;   // wave id
    const int j0   = g * 2;
    const int j1   = g * 2 + 1;

    const int kr = lane >> 3;        // k-row (0..7)
    const int d8 = lane & 7;         // d-octet: d = d8*8 .. d8*8+7

    // neighbor ids: lanes 0-31 -> j0's k, lanes 32-63 -> j1's k
    const int jj = (lane < 32) ? j0 : j1;
    const int idxreg = nbrs[((size_t)m * NN + jj) * KK + (lane & 31)];

    // ---- hoisted score-gather: all row ids + all 8 uint4 loads in flight --
    int sk0[4], sk1[4];
    #pragma unroll
    for (int i = 0; i < 4; ++i) {
        const int k = i * 8 + kr;
        sk0[i] = __shfl(idxreg, k, 64);
        sk1[i] = __shfl(idxreg, 32 + k, 64);
    }
    uint4 P0[4], P1[4];
    #pragma unroll
    for (int i = 0; i < 4; ++i) {
        P0[i] = ((const uint4*)(PnB + ((size_t)m * NN + sk0[i]) * DD))[d8];
        P1[i] = ((const uint4*)(PnB + ((size_t)m * NN + sk1[i]) * DD))[d8];
    }

    // ---- hoisted H-agg gathers: all 64 row-words issued NOW; consumed
    // after softmax. Latency hides under the score/softmax VALU phase. ----
    unsigned int g0[KK], g1[KK];
    #pragma unroll
    for (int k = 0; k < KK; ++k) {
        const int ja = __builtin_amdgcn_readlane(idxreg, k);
        const int jb = __builtin_amdgcn_readlane(idxreg, 32 + k);
        g0[k] = ((const unsigned int*)(otherB + (size_t)ja * ED))[lane];
        g1[k] = ((const unsigned int*)(otherB + (size_t)jb * ED))[lane];
    }

    // ES rows (exp2-domain, from proj) and X, as packed (even,odd) pairs.
    f32x2 S0v[4], S1v[4], m2Xv[4];
    float sumX;
    {
        const float4 a0 = *(const float4*)(S + ((size_t)m * NN + j0) * DD + d8 * 8);
        const float4 a1 = *(const float4*)(S + ((size_t)m * NN + j0) * DD + d8 * 8 + 4);
        const float4 b0 = *(const float4*)(S + ((size_t)m * NN + j1) * DD + d8 * 8);
        const float4 b1 = *(const float4*)(S + ((size_t)m * NN + j1) * DD + d8 * 8 + 4);
        const float4 x0 = *(const float4*)(Xv + (size_t)m * DD + d8 * 8);
        const float4 x1 = *(const float4*)(Xv + (size_t)m * DD + d8 * 8 + 4);
        S0v[0] = (f32x2){a0.x, a0.y}; S0v[1] = (f32x2){a0.z, a0.w};
        S0v[2] = (f32x2){a1.x, a1.y}; S0v[3] = (f32x2){a1.z, a1.w};
        S1v[0] = (f32x2){b0.x, b0.y}; S1v[1] = (f32x2){b0.z, b0.w};
        S1v[2] = (f32x2){b1.x, b1.y}; S1v[3] = (f32x2){b1.z, b1.w};
        m2Xv[0] = (f32x2){-2.0f * x0.x, -2.0f * x0.y};
        m2Xv[1] = (f32x2){-2.0f * x0.z, -2.0f * x0.w};
        m2Xv[2] = (f32x2){-2.0f * x1.x, -2.0f * x1.y};
        m2Xv[3] = (f32x2){-2.0f * x1.z, -2.0f * x1.w};
        sumX = ((x0.x + x0.y) + (x0.z + x0.w)) + ((x1.x + x1.y) + (x1.z + x1.w));
    }
    const float2 hs0 = ((const float2*)(src + (size_t)j0 * ED))[lane];
    const float2 hs1 = ((const float2*)(src + (size_t)j1 * ED))[lane];

    const f32x2 ones = {1.0f, 1.0f};
    float ea0[4], ea1[4];  // row kr handles k = i*8 + kr
    #pragma unroll
    for (int i = 0; i < 4; ++i) {
        const unsigned int pw0[4] = {P0[i].x, P0[i].y, P0[i].z, P0[i].w};
        const unsigned int pw1[4] = {P1[i].x, P1[i].y, P1[i].z, P1[i].w};
        f32x2 q0v = {sumX, 0.0f};
        f32x2 q1v = {sumX, 0.0f};
        #pragma unroll
        for (int c = 0; c < 4; ++c) {
            // X*tanh contribution: arg's exp2 = ES*EP (both precomputed)
            const f32x2 p0 = {bflo(pw0[c]), bfhi(pw0[c])};
            const f32x2 p1 = {bflo(pw1[c]), bfhi(pw1[c])};
            const f32x2 t0 = FMA2(p0, S0v[c], ones);
            const f32x2 t1 = FMA2(p1, S1v[c], ones);
            f32x2 r0, r1;
            r0.x = __builtin_amdgcn_rcpf(t0.x);
            r0.y = __builtin_amdgcn_rcpf(t0.y);
            r1.x = __builtin_amdgcn_rcpf(t1.x);
            r1.y = __builtin_amdgcn_rcpf(t1.y);
            q0v = FMA2(m2Xv[c], r0, q0v);
            q1v = FMA2(m2Xv[c], r1, q1v);
        }
        float q0 = q0v.x + q0v.y;
        float q1 = q1v.x + q1v.y;
        // d8-group tree sum via DPP
        q0 = dpp_add_f<0xB1>(q0);   q1 = dpp_add_f<0xB1>(q1);   // xor1
        q0 = dpp_add_f<0x4E>(q0);   q1 = dpp_add_f<0x4E>(q1);   // xor2
        q0 = dpp_add_f<0x141>(q0);  q1 = dpp_add_f<0x141>(q1);  // half_mirror
        ea0[i] = q0;
        ea1[i] = q1;
    }

    // softmax x2 with the reference's full-axis baseline
    const float baseline = (m == 0) ? -1e-9f : (1.0f / (float)NN);
    float mx0 = ea0[0], mx1 = ea1[0];
    #pragma unroll
    for (int i = 1; i < 4; ++i) { mx0 = fmaxf(mx0, ea0[i]); mx1 = fmaxf(mx1, ea1[i]); }
    mx0 = fmaxf(mx0, dpp_mov_f<0x128>(mx0));          // xor8 via row_ror:8
    mx1 = fmaxf(mx1, dpp_mov_f<0x128>(mx1));
    mx0 = fmaxf(mx0, __shfl_xor(mx0, 16, 64));
    mx1 = fmaxf(mx1, __shfl_xor(mx1, 16, 64));
    mx0 = fmaxf(mx0, __shfl_xor(mx0, 32, 64));
    mx1 = fmaxf(mx1, __shfl_xor(mx1, 32, 64));
    mx0 = fmaxf(mx0, baseline);
    mx1 = fmaxf(mx1, baseline);
    float sum0 = 0.0f, sum1 = 0.0f;
    #pragma unroll
    for (int i = 0; i < 4; ++i) {
        ea0[i] = __expf(ea0[i] - mx0); sum0 += ea0[i];
        ea1[i] = __expf(ea1[i] - mx1); sum1 += ea1[i];
    }
    sum0 = dpp_add_f<0x128>(sum0);                    // xor8 via row_ror:8
    sum1 = dpp_add_f<0x128>(sum1);
    sum0 += __shfl_xor(sum0, 16, 64);  sum1 += __shfl_xor(sum1, 16, 64);
    sum0 += __shfl_xor(sum0, 32, 64);  sum1 += __shfl_xor(sum1, 32, 64);
    const float inv0 =
        __builtin_amdgcn_rcpf(sum0 + (float)(NN - KK) * __expf(baseline - mx0));
    const float inv1 =
        __builtin_amdgcn_rcpf(sum1 + (float)(NN - KK) * __expf(baseline - mx1));
    #pragma unroll
    for (int i = 0; i < 4; ++i) { ea0[i] *= inv0; ea1[i] *= inv1; }

    // H aggregation on resident registers: lane covers elements
    // {2*lane, 2*lane+1}; A for k lives in e-index k>>3 of row k&7.
    f32x2 ha = {hs0.x, hs0.y};
    f32x2 hb = {hs1.x, hs1.y};
    #pragma unroll
    for (int k = 0; k < KK; ++k) {
        const float a0 = readlane_f(ea0[k >> 3], (k & 7) * 8);
        const float a1 = readlane_f(ea1[k >> 3], (k & 7) * 8);
        const f32x2 av0 = {a0, a0};
        const f32x2 av1 = {a1, a1};
        const f32x2 e0 = {bflo(g0[k]), bfhi(g0[k])};
        const f32x2 e1 = {bflo(g1[k]), bfhi(g1[k])};
        ha = FMA2(av0, e0, ha);
        hb = FMA2(av1, e1, hb);
    }
    const unsigned int hu0 =
        (unsigned int)f2bf(ha.x) | ((unsigned int)f2bf(ha.y) << 16);
    const unsigned int hu1 =
        (unsigned int)f2bf(hb.x) | ((unsigned int)f2bf(hb.y) << 16);
    ((unsigned int*)(HoutB + ((size_t)m * NN + j0) * ED))[lane] = hu0;
    ((unsigned int*)(HoutB + ((size_t)m * NN + j1) * ED))[lane] = hu1;

    // stage the same bf16-packed H rows for the in-block sem MFMA
    lh[w * 2    ][lane] = hu0;
    lh[w * 2 + 1][lane] = hu1;
    __syncthreads();

    // ---- fused sem stage: waves 0-3, n-tile t = w (d = t*16 + nrow) ----
    if (w < 4) {
        const int nrow = lane & 15;
        const int quad = lane >> 4;
        const short8* B8 = (const short8*)(WqT + (size_t)m * DD * ED);
        const short8* A8 = (const short8*)&lh[nrow][0];   // 272B row stride
        f32x4 acc = {0.f, 0.f, 0.f, 0.f};
        #pragma unroll
        for (int kq = 0; kq < 4; ++kq) {
            const short8 a = A8[kq * 4 + quad];
            const short8 b = B8[(w * 16 + nrow) * 16 + kq * 4 + quad];
            acc = __builtin_amdgcn_mfma_f32_16x16x32_bf16(a, b, acc, 0, 0, 0);
        }
        const int d = w * 16 + nrow;
        const float bq = Bq[m * DD + d];
        const float qv = Qv[m * DD + d];
        float part = 0.0f;
        #pragma unroll
        for (int reg = 0; reg < 4; ++reg)
            part = fmaf(ftanh(acc[reg] + bq), qv, part);
        #pragma unroll
        for (int off = 32; off; off >>= 1) part += __shfl_xor(part, off, 64);
        if (lane == 0) red_sh[w] = part;
    }
    __syncthreads();
    if (tid == 0)
        bp[m * 512 + blockIdx.x] =
            (red_sh[0] + red_sh[1]) + (red_sh[2] + red_sh[3]);
}

// -------------------------------------------------------------------------
// combine_proj v2: phase-0 combine fused with phase-1 EP projection,
// PARALLEL ACROSS m. grid: (NN/64, MM), block 256. Every block recomputes
// the combine for its 64 rows in registers (cheap, deterministic); only
// blockIdx.y==0 writes out0/oB; each block projects its own m:
// oB-rows @ Wp1[m] -> exp2 -> PnB[m].
// -------------------------------------------------------------------------
__global__ __launch_bounds__(256) void combine_proj(
    const unsigned short* __restrict__ HB,   // [MM,NN,ED] bf16
    const float* __restrict__ bp,            // [MM*512] partials
    float* __restrict__ outp,                // out0 f32 [NN,ED]
    unsigned short* __restrict__ outB,       // oB bf16 [NN,ED]
    const unsigned short* __restrict__ WtE,  // PT+MED [MM,DD,ED] bf16
    unsigned short* __restrict__ EPo)        // PnB [MM,NN,DD] bf16 (EP1)
{
    __shared__ float bw_sh[4];
    const int tid = threadIdx.x;
    if (tid < 64) {
        const int m = tid >> 4, t = tid & 15;
        float s = 0.0f;
        #pragma unroll
        for (int i = 0; i < 32; ++i)
            s += bp[m * 512 + t + i * 16];
        s += __shfl_xor(s, 1, 64);
        s += __shfl_xor(s, 2, 64);
        s += __shfl_xor(s, 4, 64);
        s += __shfl_xor(s, 8, 64);
        const float v = s * (1.0f / (float)NN);
        float mx = v;
        mx = fmaxf(mx, __shfl_xor(mx, 16, 64));
        mx = fmaxf(mx, __shfl_xor(mx, 32, 64));
        const float e = expf(v - mx);
        float es = e;
        es += __shfl_xor(es, 16, 64);
        es += __shfl_xor(es, 32, 64);
        if (t == 0) bw_sh[m] = e / es;
    }
    __syncthreads();
    const float bw0 = bw_sh[0], bw1 = bw_sh[1], bw2 = bw_sh[2], bw3 = bw_sh[3];

    const int mB   = blockIdx.y;               // this block's metapath
    const bool writer = (mB == 0);
    const int wave = tid >> 6;
    const int lane = tid & 63;
    const int nrow = lane & 15;
    const int quad = lane >> 4;
    const int r0   = blockIdx.x * 64 + wave * 16;
    const int r    = r0 + nrow;               // the row this lane combines
    const size_t st = (size_t)NN * ED;

    // combine 32 elems of row r (cols kq*32+quad*8 .. +7) — exactly the
    // MFMA A-fragment footprint of lane (nrow, quad) for rows r0..r0+15.
    short8 afrag[4];
    #pragma unroll
    for (int kq = 0; kq < 4; ++kq) {
        const int col = kq * 32 + quad * 8;
        const size_t off = (size_t)r * ED + col;
        const uint4 v0 = *(const uint4*)(HB + 0 * st + off);
        const uint4 v1 = *(const uint4*)(HB + 1 * st + off);
        const uint4 v2 = *(const uint4*)(HB + 2 * st + off);
        const uint4 v3 = *(const uint4*)(HB + 3 * st + off);
        const unsigned int u0[4] = {v0.x, v0.y, v0.z, v0.w};
        const unsigned int u1[4] = {v1.x, v1.y, v1.z, v1.w};
        const unsigned int u2[4] = {v2.x, v2.y, v2.z, v2.w};
        const unsigned int u3[4] = {v3.x, v3.y, v3.z, v3.w};
        float a[8];
        #pragma unroll
        for (int c = 0; c < 4; ++c) {
            a[2*c]   = fmaf(bw0, bflo(u0[c]), fmaf(bw1, bflo(u1[c]),
                       fmaf(bw2, bflo(u2[c]), bw3 * bflo(u3[c]))));
            a[2*c+1] = fmaf(bw0, bfhi(u0[c]), fmaf(bw1, bfhi(u1[c]),
                       fmaf(bw2, bfhi(u2[c]), bw3 * bfhi(u3[c]))));
        }
        uint4 ob;
        ob.x = (unsigned int)f2bf(a[0]) | ((unsigned int)f2bf(a[1]) << 16);
        ob.y = (unsigned int)f2bf(a[2]) | ((unsigned int)f2bf(a[3]) << 16);
        ob.z = (unsigned int)f2bf(a[4]) | ((unsigned int)f2bf(a[5]) << 16);
        ob.w = (unsigned int)f2bf(a[6]) | ((unsigned int)f2bf(a[7]) << 16);
        if (writer) {
            float4 o1; o1.x = a[0]; o1.y = a[1]; o1.z = a[2]; o1.w = a[3];
            float4 o2; o2.x = a[4]; o2.y = a[5]; o2.z = a[6]; o2.w = a[7];
            *(float4*)(outp + off)     = o1;
            *(float4*)(outp + off + 4) = o2;
            *(uint4*)(outB + off) = ob;
        }
        union { uint4 u; short8 s; } pk;
        pk.u = ob;
        afrag[kq] = pk.s;
    }

    // EP projection for THIS block's m: oB(rows r0..r0+15) @ Wp1[mB].
    const short8* B8 = (const short8*)(WtE + (size_t)mB * DD * ED);
    f32x4 acc0 = {0.f, 0.f, 0.f, 0.f};
    f32x4 acc1 = {0.f, 0.f, 0.f, 0.f};
    f32x4 acc2 = {0.f, 0.f, 0.f, 0.f};
    f32x4 acc3 = {0.f, 0.f, 0.f, 0.f};
    #pragma unroll
    for (int kq = 0; kq < 4; ++kq) {
        const short8 a = afrag[kq];
        const short8 w0 = B8[(0 * 16 + nrow) * 16 + kq * 4 + quad];
        const short8 w1 = B8[(1 * 16 + nrow) * 16 + kq * 4 + quad];
        const short8 w2 = B8[(2 * 16 + nrow) * 16 + kq * 4 + quad];
        const short8 w3 = B8[(3 * 16 + nrow) * 16 + kq * 4 + quad];
        acc0 = __builtin_amdgcn_mfma_f32_16x16x32_bf16(a, w0, acc0, 0, 0, 0);
        acc1 = __builtin_amdgcn_mfma_f32_16x16x32_bf16(a, w1, acc1, 0, 0, 0);
        acc2 = __builtin_amdgcn_mfma_f32_16x16x32_bf16(a, w2, acc2, 0, 0, 0);
        acc3 = __builtin_amdgcn_mfma_f32_16x16x32_bf16(a, w3, acc3, 0, 0, 0);
    }
    f32x4 accs[4] = {acc0, acc1, acc2, acc3};
    #pragma unroll
    for (int t = 0; t < 4; ++t) {
        const int d = t * 16 + nrow;
        #pragma unroll
        for (int reg = 0; reg < 4; ++reg) {
            const int rr = r0 + quad * 4 + reg;
            EPo[((size_t)mB * NN + rr) * DD + d] =
                f2bf(EXP2R(accs[t][reg] * C2LOG2E));
        }
    }
}

// -------------------------------------------------------------------------
// combine: final phase-1 combine (out1 only). grid: (NN*ED/4/256), block 256.
// -------------------------------------------------------------------------
__global__ __launch_bounds__(256) void combine_kernel(
    const unsigned short* __restrict__ HB,  // [MM,NN,ED] bf16
    const float* __restrict__ bp,           // [MM*512] partials
    float* __restrict__ outp)               // [NN,ED] f32
{
    __shared__ float bw_sh[4];
    const int tid = threadIdx.x;
    if (tid < 64) {
        const int m = tid >> 4, t = tid & 15;
        float s = 0.0f;
        #pragma unroll
        for (int i = 0; i < 32; ++i)
            s += bp[m * 512 + t + i * 16];
        s += __shfl_xor(s, 1, 64);
        s += __shfl_xor(s, 2, 64);
        s += __shfl_xor(s, 4, 64);
        s += __shfl_xor(s, 8, 64);
        const float v = s * (1.0f / (float)NN);
        float mx = v;
        mx = fmaxf(mx, __shfl_xor(mx, 16, 64));
        mx = fmaxf(mx, __shfl_xor(mx, 32, 64));
        const float e = expf(v - mx);
        float es = e;
        es += __shfl_xor(es, 16, 64);
        es += __shfl_xor(es, 32, 64);
        if (t == 0) bw_sh[m] = e / es;
    }
    __syncthreads();

    const int i = blockIdx.x * 256 + tid;           // uint2 (4-elem) index
    const size_t st = (size_t)NN * ED / 4;
    const uint2* h = (const uint2*)HB;
    float r0 = 0.f, r1 = 0.f, r2 = 0.f, r3 = 0.f;
    #pragma unroll
    for (int s = 0; s < MM; ++s) {
        const float b = bw_sh[s];
        const uint2 v = h[s * st + i];
        r0 = fmaf(b, bflo(v.x), r0);
        r1 = fmaf(b, bfhi(v.x), r1);
        r2 = fmaf(b, bflo(v.y), r2);
        r3 = fmaf(b, bfhi(v.y), r3);
    }
    float4 o; o.x = r0; o.y = r1; o.z = r2; o.w = r3;
    ((float4*)outp)[i] = o;
}

// -------------------------------------------------------------------------
extern "C" void kernel_launch(void* const* d_in, const int* in_sizes, int n_in,
                              void* d_out, int out_size, void* d_ws, size_t ws_size,
                              hipStream_t stream)
{
    // dict order: user, product, V, X, W_p, B_p, W_q, B_q, Q, user_nbrs, product_nbrs
    const float* user    = (const float*)d_in[0];
    const float* product = (const float*)d_in[1];
    const float* V   = (const float*)d_in[2];
    const float* X   = (const float*)d_in[3];
    const float* W_p = (const float*)d_in[4];
    const float* B_p = (const float*)d_in[5];
    const float* W_q = (const float*)d_in[6];
    const float* B_q = (const float*)d_in[7];
    const float* Q   = (const float*)d_in[8];
    const int* user_nbrs    = (const int*)d_in[9];
    const int* product_nbrs = (const int*)d_in[10];

    float* out  = (float*)d_out;            // [2,NN,ED] f32
    float* out0 = out;
    float* out1 = out + (size_t)NN * ED;

    // workspace layout
    float* ws = (float*)d_ws;
    float* bp = ws;                               // MM*512 = 2048
    float* S  = bp + 2048;                        // MM*NN*DD f32 (ES phase0)
    float* S2 = S + (size_t)MM * NN * DD;         // MM*NN*DD f32 (ES phase1)
    unsigned short* us = (unsigned short*)(S2 + (size_t)MM * NN * DD);
    unsigned short* PnB      = us;                             // MM*NN*DD (EP)
    unsigned short* HB       = PnB + (size_t)MM * NN * DD;     // MM*NN*ED
    unsigned short* userB    = HB + (size_t)MM * NN * ED;      // NN*ED
    unsigned short* productB = userB + (size_t)NN * ED;        // NN*ED
    unsigned short* oB       = productB + (size_t)NN * ED;     // NN*ED
    unsigned short* VT       = oB + (size_t)NN * ED;           // 2*MM*DD*ED
    unsigned short* PT       = VT + (size_t)2 * MM * DD * ED;
    unsigned short* QT       = PT + (size_t)2 * MM * DD * ED;

    const size_t MED = (size_t)MM * ED * DD;   // per-phase weight slice
    const size_t MD  = (size_t)MM * DD;

    const dim3 gP(NN / 64, MM, 3);             // 3-slice proj grid (phase 0)
    const dim3 gA(NN / 16, MM);                // attn+sem grid (16 nodes/block)
    const dim3 gC(NN / 64, MM);                // combine_proj grid
    const int cBlocks = (NN * ED / 4) / 256;   // 1024

    // ---------------- prep: conversions + transposes, one launch ----------
    prep_kernel<<<dim3(1024, 5), 256, 0, stream>>>(user, userB, product, productB,
                                                   V, VT, W_p, PT, W_q, QT);

    // proj: ES0(user), EP0(product), ES1(product — phase-1, independent)
    proj3_mfma<<<gP, 256, 0, stream>>>(userB, VT, B_p, S,
                                       productB, PT, PnB,
                                       VT + MED, B_p + MD, S2);

    // phase 0 attn + fused sem
    attn_sem_kernel<<<gA, 512, 0, stream>>>(user, productB, user_nbrs,
                                            S, PnB, X, HB,
                                            QT, B_q, Q, bp);

    // phase-0 combine fused with phase-1 EP projection (parallel across m)
    combine_proj<<<gC, 256, 0, stream>>>(HB, bp, out0, oB,
                                         PT + MED, PnB);

    // phase 1 attn + fused sem (attends over updated user embeddings oB)
    attn_sem_kernel<<<gA, 512, 0, stream>>>(product, oB, product_nbrs,
                                            S2, PnB, X + MD, HB,
                                            QT + MED, B_q + MD, Q + MD, bp);

    // final combine (out1)
    combine_kernel<<<cBlocks, 256, 0, stream>>>(HB, bp, out1);
}

// Round 8
// 179.535 us; speedup vs baseline: 1.2015x; 1.2015x over previous
//
#include <hip/hip_runtime.h>
#include <hip/hip_bf16.h>

// Problem constants (fixed by the reference)
#define NN 8192   // nodes per side
#define ED 128    // embedding dim E
#define DD 64     // attention dim D
#define KK 32     // neighbors per node
#define MM 4      // metapaths

typedef __attribute__((ext_vector_type(8))) short short8;   // 8 bf16 (4 VGPRs)
typedef __attribute__((ext_vector_type(4))) float f32x4;    // MFMA acc
typedef __attribute__((ext_vector_type(2))) float f32x2;    // packed f32 pair

// raw v_exp_f32 (2^x); fallback multiplies back to e-base expf
#if __has_builtin(__builtin_amdgcn_exp2f)
#define EXP2R(x) __builtin_amdgcn_exp2f(x)
#else
#define EXP2R(x) __expf((x) * 0.6931471805599453f)
#endif
#define C2LOG2E 2.8853900817779268f   // 2*log2(e)

#if __has_builtin(__builtin_elementwise_fma)
#define FMA2(a, b, c) __builtin_elementwise_fma((a), (b), (c))
#else
__device__ __forceinline__ f32x2 FMA2(f32x2 a, f32x2 b, f32x2 c)
{
    f32x2 r;
    r.x = fmaf(a.x, b.x, c.x);
    r.y = fmaf(a.y, b.y, c.y);
    return r;
}
#endif

// tanh from pre-scaled arg v = x*2*log2(e): 1 - 2*rcp(2^v + 1)
__device__ __forceinline__ float ftanh_pre(float v)
{
    return fmaf(-2.0f, __builtin_amdgcn_rcpf(EXP2R(v) + 1.0f), 1.0f);
}
// plain fast tanh (sem epilogue)
__device__ __forceinline__ float ftanh(float x)
{
    return ftanh_pre(x * C2LOG2E);
}

__device__ __forceinline__ unsigned short f2bf(float x)
{
    __hip_bfloat16 b = __float2bfloat16(x);
    return *reinterpret_cast<unsigned short*>(&b);
}
__device__ __forceinline__ float bflo(unsigned int u) { return __uint_as_float(u << 16); }
__device__ __forceinline__ float bfhi(unsigned int u) { return __uint_as_float(u & 0xFFFF0000u); }
__device__ __forceinline__ float shfl_f(float v, int srcLane)
{
    return __shfl(v, srcLane, 64);
}

// DPP helpers. CTRL: 0xB1 = quad_perm xor1, 0x4E = quad_perm xor2,
// 0x141 = row_half_mirror (xor4-equivalent for 8-lane tree sums),
// 0x128 = row_ror:8 ((lane+8)%16 == lane^8 within a 16-lane row).
// VALU-only — replaces ds_bpermute shuffle hops.
template <int CTRL>
__device__ __forceinline__ float dpp_mov_f(float x)
{
    return __int_as_float(__builtin_amdgcn_update_dpp(
        0, __float_as_int(x), CTRL, 0xF, 0xF, true));
}
template <int CTRL>
__device__ __forceinline__ float dpp_add_f(float x)
{
    return x + dpp_mov_f<CTRL>(x);
}

// -------------------------------------------------------------------------
// prep_kernel: one launch for all input reformatting.
//  y=0: user f32->bf16   y=1: product f32->bf16   (x < 1024, 4 elems/thr)
//  y=2/3/4: V/W_p/W_q f32 [S,ED,DD] -> bf16 [S,DD,ED]  (x < 256)
// -------------------------------------------------------------------------
__global__ __launch_bounds__(256) void prep_kernel(
    const float* __restrict__ user, unsigned short* __restrict__ userB,
    const float* __restrict__ product, unsigned short* __restrict__ productB,
    const float* __restrict__ V, unsigned short* __restrict__ VT,
    const float* __restrict__ Wp, unsigned short* __restrict__ PT,
    const float* __restrict__ Wq, unsigned short* __restrict__ QT)
{
    const int y = blockIdx.y;
    if (y < 2) {
        const float* in = y ? product : user;
        unsigned short* out = y ? productB : userB;
        const int i = blockIdx.x * 256 + threadIdx.x;
        const float4 v = ((const float4*)in)[i];
        uint2 o;
        o.x = (unsigned int)f2bf(v.x) | ((unsigned int)f2bf(v.y) << 16);
        o.y = (unsigned int)f2bf(v.z) | ((unsigned int)f2bf(v.w) << 16);
        ((uint2*)out)[i] = o;
    } else {
        if (blockIdx.x >= 256) return;
        const float* in = (y == 2) ? V : (y == 3) ? Wp : Wq;
        unsigned short* out = (y == 2) ? VT : (y == 3) ? PT : QT;
        const int gid = blockIdx.x * 256 + threadIdx.x;
        const int s   = gid >> 13;          // ED*DD = 8192
        const int rem = gid & 8191;
        const int e   = rem >> 6;
        const int d   = rem & 63;
        out[((size_t)s * DD + d) * ED + e] = f2bf(in[gid]);
    }
}

// -------------------------------------------------------------------------
// proj3_mfma: three projection slices in ONE phase-0 launch (blockIdx.z):
//   z=0: ES0 = exp2((user  @ V0 + B0) * C) -> f32 outF0  (phase-0 attn)
//   z=1: EP0 = exp2((prod  @ Wp0)     * C) -> bf16 outB1 (phase-0 attn)
//   z=2: ES1 = exp2((prod  @ V1 + B1) * C) -> f32 outF2  (phase-1 attn;
//        independent of phase 0, so computed here off the critical path)
// grid: (NN/64, MM, 3).
// -------------------------------------------------------------------------
__global__ __launch_bounds__(256) void proj3_mfma(
    const unsigned short* __restrict__ emb0,  // userB [NN,ED]
    const unsigned short* __restrict__ Wt0,   // VT0 [MM,DD,ED]
    const float* __restrict__ Bias0,          // B_p0 [MM,DD]
    float* __restrict__ outF0,                // S  (ES0)
    const unsigned short* __restrict__ emb1,  // productB [NN,ED]
    const unsigned short* __restrict__ Wt1,   // PT0 [MM,DD,ED]
    unsigned short* __restrict__ outB1,       // PnB (EP0)
    const unsigned short* __restrict__ Wt2,   // VT1 [MM,DD,ED]
    const float* __restrict__ Bias2,          // B_p1 [MM,DD]
    float* __restrict__ outF2)                // S2 (ES1)
{
    const int z    = blockIdx.z;
    const int m    = blockIdx.y;
    const int tid  = threadIdx.x;
    const int wave = tid >> 6;
    const int lane = tid & 63;
    const int nrow = lane & 15;
    const int quad = lane >> 4;
    const int r0   = blockIdx.x * 64 + wave * 16;

    const unsigned short* embB = (z == 0) ? emb0 : emb1;
    const unsigned short* WtB  = (z == 0) ? Wt0 : (z == 1) ? Wt1 : Wt2;

    const short8* A8 = (const short8*)(embB + (size_t)(r0 + nrow) * ED);
    const short8* B8 = (const short8*)(WtB + (size_t)m * DD * ED);

    f32x4 acc0 = {0.f, 0.f, 0.f, 0.f};
    f32x4 acc1 = {0.f, 0.f, 0.f, 0.f};
    f32x4 acc2 = {0.f, 0.f, 0.f, 0.f};
    f32x4 acc3 = {0.f, 0.f, 0.f, 0.f};

    #pragma unroll
    for (int kq = 0; kq < 4; ++kq) {
        const short8 a = A8[kq * 4 + quad];
        const short8 b0 = B8[(0 * 16 + nrow) * 16 + kq * 4 + quad];
        const short8 b1 = B8[(1 * 16 + nrow) * 16 + kq * 4 + quad];
        const short8 b2 = B8[(2 * 16 + nrow) * 16 + kq * 4 + quad];
        const short8 b3 = B8[(3 * 16 + nrow) * 16 + kq * 4 + quad];
        acc0 = __builtin_amdgcn_mfma_f32_16x16x32_bf16(a, b0, acc0, 0, 0, 0);
        acc1 = __builtin_amdgcn_mfma_f32_16x16x32_bf16(a, b1, acc1, 0, 0, 0);
        acc2 = __builtin_amdgcn_mfma_f32_16x16x32_bf16(a, b2, acc2, 0, 0, 0);
        acc3 = __builtin_amdgcn_mfma_f32_16x16x32_bf16(a, b3, acc3, 0, 0, 0);
    }

    f32x4 accs[4] = {acc0, acc1, acc2, acc3};
    if (z == 1) {
        #pragma unroll
        for (int t = 0; t < 4; ++t) {
            const int d = t * 16 + nrow;
            #pragma unroll
            for (int reg = 0; reg < 4; ++reg) {
                const int r = r0 + quad * 4 + reg;
                outB1[((size_t)m * NN + r) * DD + d] =
                    f2bf(EXP2R(accs[t][reg] * C2LOG2E));
            }
        }
    } else {
        const float* Bi = (z == 0) ? Bias0 : Bias2;
        float* oF       = (z == 0) ? outF0 : outF2;
        #pragma unroll
        for (int t = 0; t < 4; ++t) {
            const int d = t * 16 + nrow;
            const float bv = Bi[m * DD + d];
            #pragma unroll
            for (int reg = 0; reg < 4; ++reg) {
                const int r = r0 + quad * 4 + reg;
                oF[((size_t)m * NN + r) * DD + d] =
                    EXP2R((accs[t][reg] + bv) * C2LOG2E);
            }
        }
    }
}

// -------------------------------------------------------------------------
// attn_sem_kernel v11: HALF-WAVE node ownership. Lanes 0-31 own node j0,
// lanes 32-63 own j1 (h = lane>>5). Per half: kr = (lane&31)>>3 covers 4
// k-rows x 8 score iterations; d8 = lane&7 covers 8 d-octets.
// vs v9 (R5): single softmax stream (half the softmax instructions, one
// fewer reduce hop — halves never mix), ONE uint2 gather per k serves both
// nodes (load issues halved), 2 shfl per k instead of 4 readlanes, and
// prefetch state shrinks 24->6 VGPR. All FP ops identical in value+order.
// VGPR must stay <=64 (8 waves/EU) — R7 proved duration ~ 1/waves.
// grid: (NN/16, MM), block 512.
// -------------------------------------------------------------------------
__global__ __launch_bounds__(512) void attn_sem_kernel(
    const float* __restrict__ src,             // [NN,ED] f32
    const unsigned short* __restrict__ otherB, // [NN,ED] bf16
    const int*   __restrict__ nbrs,            // [MM,NN,KK]
    const float* __restrict__ S,               // [MM,NN,DD] f32 = ES
    const unsigned short* __restrict__ PnB,    // [MM,NN,DD] bf16 = EP
    const float* __restrict__ Xv,              // [MM,DD] f32
    unsigned short* __restrict__ HoutB,        // [MM,NN,ED] bf16
    const unsigned short* __restrict__ WqT,    // [MM,DD,ED] bf16
    const float* __restrict__ Bq,              // [MM,DD]
    const float* __restrict__ Qv,              // [MM,DD]
    float* __restrict__ bp)                    // [MM*512] beta partials
{
    // H staging: 16 rows x 64 packed-bf16 words, +4 words pad per row to
    // break the 256B-stride bank alignment for the ds_read_b128 fragments.
    __shared__ __align__(16) unsigned int lh[16][68];
    __shared__ float red_sh[4];

    const int m    = blockIdx.y;
    const int tid  = threadIdx.x;
    const int w    = tid >> 6;
    const int lane = tid & 63;
    const int l5   = lane & 31;      // lane within half
    const int h    = lane >> 5;      // half: 0 -> j0, 1 -> j1
    const int g    = blockIdx.x * 8 + w;   // wave id
    const int j    = g * 2 + h;            // this half's node

    const int kr = l5 >> 3;          // k-row (0..3): k = i*4 + kr
    const int d8 = lane & 7;         // d-octet: d = d8*8 .. d8*8+7
    const int hbase = lane & 32;     // shfl base for own half

    // neighbor ids: lane holds k = l5 of its half's node
    const int idxreg = nbrs[((size_t)m * NN + j) * KK + l5];

    // ---- hoisted score-gather: 8 row ids + 8 uint4 loads in flight ----
    int sk[8];
    #pragma unroll
    for (int i = 0; i < 8; ++i)
        sk[i] = __shfl(idxreg, hbase + i * 4 + kr, 64);
    uint4 P[8];
    #pragma unroll
    for (int i = 0; i < 8; ++i)
        P[i] = ((const uint4*)(PnB + ((size_t)m * NN + sk[i]) * DD))[d8];

    // ---- first two H-agg gathers issued now (latency under score) ----
    uint2 buf[3];
    {
        const int jk0 = __shfl(idxreg, hbase + 0, 64);
        const int jk1 = __shfl(idxreg, hbase + 1, 64);
        buf[0] = ((const uint2*)(otherB + (size_t)jk0 * ED))[l5];
        buf[1] = ((const uint2*)(otherB + (size_t)jk1 * ED))[l5];
    }

    // ES row of own node (exp2-domain) and X, as packed (even,odd) pairs.
    f32x2 Sv[4], m2Xv[4];
    float sumX;
    {
        const float4 a0 = *(const float4*)(S + ((size_t)m * NN + j) * DD + d8 * 8);
        const float4 a1 = *(const float4*)(S + ((size_t)m * NN + j) * DD + d8 * 8 + 4);
        const float4 x0 = *(const float4*)(Xv + (size_t)m * DD + d8 * 8);
        const float4 x1 = *(const float4*)(Xv + (size_t)m * DD + d8 * 8 + 4);
        Sv[0] = (f32x2){a0.x, a0.y}; Sv[1] = (f32x2){a0.z, a0.w};
        Sv[2] = (f32x2){a1.x, a1.y}; Sv[3] = (f32x2){a1.z, a1.w};
        m2Xv[0] = (f32x2){-2.0f * x0.x, -2.0f * x0.y};
        m2Xv[1] = (f32x2){-2.0f * x0.z, -2.0f * x0.w};
        m2Xv[2] = (f32x2){-2.0f * x1.x, -2.0f * x1.y};
        m2Xv[3] = (f32x2){-2.0f * x1.z, -2.0f * x1.w};
        sumX = ((x0.x + x0.y) + (x0.z + x0.w)) + ((x1.x + x1.y) + (x1.z + x1.w));
    }
    // src row of own node: lane covers elems 4*l5 .. 4*l5+3
    const float4 hs = ((const float4*)(src + (size_t)j * ED))[l5];

    const f32x2 ones = {1.0f, 1.0f};
    float ea[8];   // score for k = i*4 + kr (replicated over d8 after tree)
    #pragma unroll
    for (int i = 0; i < 8; ++i) {
        const unsigned int pw[4] = {P[i].x, P[i].y, P[i].z, P[i].w};
        f32x2 qv = {sumX, 0.0f};
        #pragma unroll
        for (int c = 0; c < 4; ++c) {
            // X*tanh contribution: arg's exp2 = ES*EP (both precomputed)
            const f32x2 p = {bflo(pw[c]), bfhi(pw[c])};
            const f32x2 t = FMA2(p, Sv[c], ones);
            f32x2 r;
            r.x = __builtin_amdgcn_rcpf(t.x);
            r.y = __builtin_amdgcn_rcpf(t.y);
            qv = FMA2(m2Xv[c], r, qv);
        }
        float q = qv.x + qv.y;
        // d8-group (8-lane) tree sum via DPP
        q = dpp_add_f<0xB1>(q);    // xor1
        q = dpp_add_f<0x4E>(q);    // xor2
        q = dpp_add_f<0x141>(q);   // half_mirror
        ea[i] = q;
    }

    // softmax (single stream per half) with the reference's full-axis baseline
    const float baseline = (m == 0) ? -1e-9f : (1.0f / (float)NN);
    float mx = ea[0];
    #pragma unroll
    for (int i = 1; i < 8; ++i) mx = fmaxf(mx, ea[i]);
    mx = fmaxf(mx, dpp_mov_f<0x128>(mx));       // xor8 (kr bit 0)
    mx = fmaxf(mx, __shfl_xor(mx, 16, 64));     // xor16 (kr bit 1) — halves never mix
    mx = fmaxf(mx, baseline);
    float sum = 0.0f;
    #pragma unroll
    for (int i = 0; i < 8; ++i) {
        ea[i] = __expf(ea[i] - mx);
        sum += ea[i];
    }
    sum = dpp_add_f<0x128>(sum);
    sum += __shfl_xor(sum, 16, 64);
    const float inv =
        __builtin_amdgcn_rcpf(sum + (float)(NN - KK) * __expf(baseline - mx));
    #pragma unroll
    for (int i = 0; i < 8; ++i) ea[i] *= inv;

    // H aggregation: ONE uint2 gather per k serves both halves. Lane covers
    // elems 4*l5..4*l5+3 of its node. A for k lives at source lane
    // hbase + (k&3)*8 in register ea[k>>2] (replicated over d8).
    // 3-deep rotating prefetch; slots compile-time after unroll.
    f32x2 hA = {hs.x, hs.y};
    f32x2 hB = {hs.z, hs.w};
    #pragma unroll
    for (int k = 0; k < KK; ++k) {
        const int slot = k % 3;
        if (k < KK - 2) {
            const int jk = __shfl(idxreg, hbase + k + 2, 64);
            buf[(k + 2) % 3] = ((const uint2*)(otherB + (size_t)jk * ED))[l5];
        }
        const float a = __shfl(ea[k >> 2], hbase + (k & 3) * 8, 64);
        const f32x2 av = {a, a};
        const f32x2 elo = {bflo(buf[slot].x), bfhi(buf[slot].x)};
        const f32x2 ehi = {bflo(buf[slot].y), bfhi(buf[slot].y)};
        hA = FMA2(av, elo, hA);
        hB = FMA2(av, ehi, hB);
    }
    uint2 hu;
    hu.x = (unsigned int)f2bf(hA.x) | ((unsigned int)f2bf(hA.y) << 16);
    hu.y = (unsigned int)f2bf(hB.x) | ((unsigned int)f2bf(hB.y) << 16);
    ((uint2*)(HoutB + ((size_t)m * NN + j) * ED))[l5] = hu;

    // stage the same bf16-packed H row for the in-block sem MFMA
    *(uint2*)&lh[w * 2 + h][l5 * 2] = hu;
    __syncthreads();

    // ---- fused sem stage: waves 0-3, n-tile t = w (d = t*16 + nrow) ----
    if (w < 4) {
        const int nrow = lane & 15;
        const int quad = lane >> 4;
        const short8* B8 = (const short8*)(WqT + (size_t)m * DD * ED);
        const short8* A8 = (const short8*)&lh[nrow][0];   // 272B row stride
        f32x4 acc = {0.f, 0.f, 0.f, 0.f};
        #pragma unroll
        for (int kq = 0; kq < 4; ++kq) {
            const short8 a = A8[kq * 4 + quad];
            const short8 b = B8[(w * 16 + nrow) * 16 + kq * 4 + quad];
            acc = __builtin_amdgcn_mfma_f32_16x16x32_bf16(a, b, acc, 0, 0, 0);
        }
        const int d = w * 16 + nrow;
        const float bq = Bq[m * DD + d];
        const float qv = Qv[m * DD + d];
        float part = 0.0f;
        #pragma unroll
        for (int reg = 0; reg < 4; ++reg)
            part = fmaf(ftanh(acc[reg] + bq), qv, part);
        #pragma unroll
        for (int off = 32; off; off >>= 1) part += __shfl_xor(part, off, 64);
        if (lane == 0) red_sh[w] = part;
    }
    __syncthreads();
    if (tid == 0)
        bp[m * 512 + blockIdx.x] =
            (red_sh[0] + red_sh[1]) + (red_sh[2] + red_sh[3]);
}

// -------------------------------------------------------------------------
// combine_proj v2: phase-0 combine fused with phase-1 EP projection,
// PARALLEL ACROSS m. grid: (NN/64, MM), block 256. Every block recomputes
// the combine for its 64 rows in registers (cheap, deterministic); only
// blockIdx.y==0 writes out0/oB; each block projects its own m:
// oB-rows @ Wp1[m] -> exp2 -> PnB[m].
// -------------------------------------------------------------------------
__global__ __launch_bounds__(256) void combine_proj(
    const unsigned short* __restrict__ HB,   // [MM,NN,ED] bf16
    const float* __restrict__ bp,            // [MM*512] partials
    float* __restrict__ outp,                // out0 f32 [NN,ED]
    unsigned short* __restrict__ outB,       // oB bf16 [NN,ED]
    const unsigned short* __restrict__ WtE,  // PT+MED [MM,DD,ED] bf16
    unsigned short* __restrict__ EPo)        // PnB [MM,NN,DD] bf16 (EP1)
{
    __shared__ float bw_sh[4];
    const int tid = threadIdx.x;
    if (tid < 64) {
        const int m = tid >> 4, t = tid & 15;
        float s = 0.0f;
        #pragma unroll
        for (int i = 0; i < 32; ++i)
            s += bp[m * 512 + t + i * 16];
        s += __shfl_xor(s, 1, 64);
        s += __shfl_xor(s, 2, 64);
        s += __shfl_xor(s, 4, 64);
        s += __shfl_xor(s, 8, 64);
        const float v = s * (1.0f / (float)NN);
        float mx = v;
        mx = fmaxf(mx, __shfl_xor(mx, 16, 64));
        mx = fmaxf(mx, __shfl_xor(mx, 32, 64));
        const float e = expf(v - mx);
        float es = e;
        es += __shfl_xor(es, 16, 64);
        es += __shfl_xor(es, 32, 64);
        if (t == 0) bw_sh[m] = e / es;
    }
    __syncthreads();
    const float bw0 = bw_sh[0], bw1 = bw_sh[1], bw2 = bw_sh[2], bw3 = bw_sh[3];

    const int mB   = blockIdx.y;               // this block's metapath
    const bool writer = (mB == 0);
    const int wave = tid >> 6;
    const int lane = tid & 63;
    const int nrow = lane & 15;
    const int quad = lane >> 4;
    const int r0   = blockIdx.x * 64 + wave * 16;
    const int r    = r0 + nrow;               // the row this lane combines
    const size_t st = (size_t)NN * ED;

    // combine 32 elems of row r (cols kq*32+quad*8 .. +7) — exactly the
    // MFMA A-fragment footprint of lane (nrow, quad) for rows r0..r0+15.
    short8 afrag[4];
    #pragma unroll
    for (int kq = 0; kq < 4; ++kq) {
        const int col = kq * 32 + quad * 8;
        const size_t off = (size_t)r * ED + col;
        const uint4 v0 = *(const uint4*)(HB + 0 * st + off);
        const uint4 v1 = *(const uint4*)(HB + 1 * st + off);
        const uint4 v2 = *(const uint4*)(HB + 2 * st + off);
        const uint4 v3 = *(const uint4*)(HB + 3 * st + off);
        const unsigned int u0[4] = {v0.x, v0.y, v0.z, v0.w};
        const unsigned int u1[4] = {v1.x, v1.y, v1.z, v1.w};
        const unsigned int u2[4] = {v2.x, v2.y, v2.z, v2.w};
        const unsigned int u3[4] = {v3.x, v3.y, v3.z, v3.w};
        float a[8];
        #pragma unroll
        for (int c = 0; c < 4; ++c) {
            a[2*c]   = fmaf(bw0, bflo(u0[c]), fmaf(bw1, bflo(u1[c]),
                       fmaf(bw2, bflo(u2[c]), bw3 * bflo(u3[c]))));
            a[2*c+1] = fmaf(bw0, bfhi(u0[c]), fmaf(bw1, bfhi(u1[c]),
                       fmaf(bw2, bfhi(u2[c]), bw3 * bfhi(u3[c]))));
        }
        uint4 ob;
        ob.x = (unsigned int)f2bf(a[0]) | ((unsigned int)f2bf(a[1]) << 16);
        ob.y = (unsigned int)f2bf(a[2]) | ((unsigned int)f2bf(a[3]) << 16);
        ob.z = (unsigned int)f2bf(a[4]) | ((unsigned int)f2bf(a[5]) << 16);
        ob.w = (unsigned int)f2bf(a[6]) | ((unsigned int)f2bf(a[7]) << 16);
        if (writer) {
            float4 o1; o1.x = a[0]; o1.y = a[1]; o1.z = a[2]; o1.w = a[3];
            float4 o2; o2.x = a[4]; o2.y = a[5]; o2.z = a[6]; o2.w = a[7];
            *(float4*)(outp + off)     = o1;
            *(float4*)(outp + off + 4) = o2;
            *(uint4*)(outB + off) = ob;
        }
        union { uint4 u; short8 s; } pk;
        pk.u = ob;
        afrag[kq] = pk.s;
    }

    // EP projection for THIS block's m: oB(rows r0..r0+15) @ Wp1[mB].
    const short8* B8 = (const short8*)(WtE + (size_t)mB * DD * ED);
    f32x4 acc0 = {0.f, 0.f, 0.f, 0.f};
    f32x4 acc1 = {0.f, 0.f, 0.f, 0.f};
    f32x4 acc2 = {0.f, 0.f, 0.f, 0.f};
    f32x4 acc3 = {0.f, 0.f, 0.f, 0.f};
    #pragma unroll
    for (int kq = 0; kq < 4; ++kq) {
        const short8 a = afrag[kq];
        const short8 w0 = B8[(0 * 16 + nrow) * 16 + kq * 4 + quad];
        const short8 w1 = B8[(1 * 16 + nrow) * 16 + kq * 4 + quad];
        const short8 w2 = B8[(2 * 16 + nrow) * 16 + kq * 4 + quad];
        const short8 w3 = B8[(3 * 16 + nrow) * 16 + kq * 4 + quad];
        acc0 = __builtin_amdgcn_mfma_f32_16x16x32_bf16(a, w0, acc0, 0, 0, 0);
        acc1 = __builtin_amdgcn_mfma_f32_16x16x32_bf16(a, w1, acc1, 0, 0, 0);
        acc2 = __builtin_amdgcn_mfma_f32_16x16x32_bf16(a, w2, acc2, 0, 0, 0);
        acc3 = __builtin_amdgcn_mfma_f32_16x16x32_bf16(a, w3, acc3, 0, 0, 0);
    }
    f32x4 accs[4] = {acc0, acc1, acc2, acc3};
    #pragma unroll
    for (int t = 0; t < 4; ++t) {
        const int d = t * 16 + nrow;
        #pragma unroll
        for (int reg = 0; reg < 4; ++reg) {
            const int rr = r0 + quad * 4 + reg;
            EPo[((size_t)mB * NN + rr) * DD + d] =
                f2bf(EXP2R(accs[t][reg] * C2LOG2E));
        }
    }
}

// -------------------------------------------------------------------------
// combine: final phase-1 combine (out1 only). grid: (NN*ED/4/256), block 256.
// -------------------------------------------------------------------------
__global__ __launch_bounds__(256) void combine_kernel(
    const unsigned short* __restrict__ HB,  // [MM,NN,ED] bf16
    const float* __restrict__ bp,           // [MM*512] partials
    float* __restrict__ outp)               // [NN,ED] f32
{
    __shared__ float bw_sh[4];
    const int tid = threadIdx.x;
    if (tid < 64) {
        const int m = tid >> 4, t = tid & 15;
        float s = 0.0f;
        #pragma unroll
        for (int i = 0; i < 32; ++i)
            s += bp[m * 512 + t + i * 16];
        s += __shfl_xor(s, 1, 64);
        s += __shfl_xor(s, 2, 64);
        s += __shfl_xor(s, 4, 64);
        s += __shfl_xor(s, 8, 64);
        const float v = s * (1.0f / (float)NN);
        float mx = v;
        mx = fmaxf(mx, __shfl_xor(mx, 16, 64));
        mx = fmaxf(mx, __shfl_xor(mx, 32, 64));
        const float e = expf(v - mx);
        float es = e;
        es += __shfl_xor(es, 16, 64);
        es += __shfl_xor(es, 32, 64);
        if (t == 0) bw_sh[m] = e / es;
    }
    __syncthreads();

    const int i = blockIdx.x * 256 + tid;           // uint2 (4-elem) index
    const size_t st = (size_t)NN * ED / 4;
    const uint2* h = (const uint2*)HB;
    float r0 = 0.f, r1 = 0.f, r2 = 0.f, r3 = 0.f;
    #pragma unroll
    for (int s = 0; s < MM; ++s) {
        const float b = bw_sh[s];
        const uint2 v = h[s * st + i];
        r0 = fmaf(b, bflo(v.x), r0);
        r1 = fmaf(b, bfhi(v.x), r1);
        r2 = fmaf(b, bflo(v.y), r2);
        r3 = fmaf(b, bfhi(v.y), r3);
    }
    float4 o; o.x = r0; o.y = r1; o.z = r2; o.w = r3;
    ((float4*)outp)[i] = o;
}

// -------------------------------------------------------------------------
extern "C" void kernel_launch(void* const* d_in, const int* in_sizes, int n_in,
                              void* d_out, int out_size, void* d_ws, size_t ws_size,
                              hipStream_t stream)
{
    // dict order: user, product, V, X, W_p, B_p, W_q, B_q, Q, user_nbrs, product_nbrs
    const float* user    = (const float*)d_in[0];
    const float* product = (const float*)d_in[1];
    const float* V   = (const float*)d_in[2];
    const float* X   = (const float*)d_in[3];
    const float* W_p = (const float*)d_in[4];
    const float* B_p = (const float*)d_in[5];
    const float* W_q = (const float*)d_in[6];
    const float* B_q = (const float*)d_in[7];
    const float* Q   = (const float*)d_in[8];
    const int* user_nbrs    = (const int*)d_in[9];
    const int* product_nbrs = (const int*)d_in[10];

    float* out  = (float*)d_out;            // [2,NN,ED] f32
    float* out0 = out;
    float* out1 = out + (size_t)NN * ED;

    // workspace layout
    float* ws = (float*)d_ws;
    float* bp = ws;                               // MM*512 = 2048
    float* S  = bp + 2048;                        // MM*NN*DD f32 (ES phase0)
    float* S2 = S + (size_t)MM * NN * DD;         // MM*NN*DD f32 (ES phase1)
    unsigned short* us = (unsigned short*)(S2 + (size_t)MM * NN * DD);
    unsigned short* PnB      = us;                             // MM*NN*DD (EP)
    unsigned short* HB       = PnB + (size_t)MM * NN * DD;     // MM*NN*ED
    unsigned short* userB    = HB + (size_t)MM * NN * ED;      // NN*ED
    unsigned short* productB = userB + (size_t)NN * ED;        // NN*ED
    unsigned short* oB       = productB + (size_t)NN * ED;     // NN*ED
    unsigned short* VT       = oB + (size_t)NN * ED;           // 2*MM*DD*ED
    unsigned short* PT       = VT + (size_t)2 * MM * DD * ED;
    unsigned short* QT       = PT + (size_t)2 * MM * DD * ED;

    const size_t MED = (size_t)MM * ED * DD;   // per-phase weight slice
    const size_t MD  = (size_t)MM * DD;

    const dim3 gP(NN / 64, MM, 3);             // 3-slice proj grid (phase 0)
    const dim3 gA(NN / 16, MM);                // attn+sem grid (16 nodes/block)
    const dim3 gC(NN / 64, MM);                // combine_proj grid
    const int cBlocks = (NN * ED / 4) / 256;   // 1024

    // ---------------- prep: conversions + transposes, one launch ----------
    prep_kernel<<<dim3(1024, 5), 256, 0, stream>>>(user, userB, product, productB,
                                                   V, VT, W_p, PT, W_q, QT);

    // proj: ES0(user), EP0(product), ES1(product — phase-1, independent)
    proj3_mfma<<<gP, 256, 0, stream>>>(userB, VT, B_p, S,
                                       productB, PT, PnB,
                                       VT + MED, B_p + MD, S2);

    // phase 0 attn + fused sem
    attn_sem_kernel<<<gA, 512, 0, stream>>>(user, productB, user_nbrs,
                                            S, PnB, X, HB,
                                            QT, B_q, Q, bp);

    // phase-0 combine fused with phase-1 EP projection (parallel across m)
    combine_proj<<<gC, 256, 0, stream>>>(HB, bp, out0, oB,
                                         PT + MED, PnB);

    // phase 1 attn + fused sem (attends over updated user embeddings oB)
    attn_sem_kernel<<<gA, 512, 0, stream>>>(product, oB, product_nbrs,
                                            S2, PnB, X + MD, HB,
                                            QT + MED, B_q + MD, Q + MD, bp);

    // final combine (out1)
    combine_kernel<<<cBlocks, 256, 0, stream>>>(HB, bp, out1);
}